// Round 10
// baseline (132.928 us; speedup 1.0000x reference)
//
#include <hip/hip_runtime.h>
#include <hip/hip_bf16.h>
#include <cstdint>

// Problem constants
#define NPTS  131072
#define NRET  65536
#define NBAT  64
#define NBUCK (1 << 18)   // buckets = top-18 bits of descending key
#define BSH   14          // d >> 14 -> bucket

// Monotone map f32 -> u32 such that ascending u32 == DESCENDING float value.
__device__ __forceinline__ unsigned int desc_key(float w) {
    unsigned int b = __float_as_uint(w);
    unsigned int s = b ^ ((unsigned int)((int)b >> 31) | 0x80000000u); // ascending
    return ~s;                                                        // descending
}

// Fused (independent pieces, zero data deps -> legal in one node):
// blocks 0..511:  zero hist+cnt (2 MiB, uint4 stores)
// blocks 512..543: exp phase. Each block REDUNDANTLY recomputes the exact max
// of w (order-independent), then e_i = f32(exp(double(w_i - m))) with numpy's
// base-128 8-lane partial sums (one thread per lane).
__global__ void k_zero_exp(const float* __restrict__ w, uint4* __restrict__ zp,
                           float* __restrict__ e_out, float* __restrict__ bs) {
    int j = blockIdx.x, tid = threadIdx.x;
    if (j < 512) {
        zp[j * 256 + tid] = make_uint4(0u, 0u, 0u, 0u);
        return;
    }
    __shared__ float smm[256];
    __shared__ float smr[256];
    // redundant exact max over all of w (float4 loads, 128 iters/thread)
    const float4* w4 = (const float4*)w;
    float m = -3.402823466e38f;
    for (int i = tid; i < NPTS / 4; i += 256) {
        float4 v = w4[i];
        m = fmaxf(m, fmaxf(fmaxf(v.x, v.y), fmaxf(v.z, v.w)));
    }
    smm[tid] = m; __syncthreads();
    for (int off = 128; off > 0; off >>= 1) {
        if (tid < off) smm[tid] = fmaxf(smm[tid], smm[tid + off]);
        __syncthreads();
    }
    m = smm[0];
    int task = (j - 512) * 256 + tid;        // 0..8191
    int base = task >> 3;                    // base block 0..1023
    int k    = task & 7;                     // numpy accumulator lane
    const float* wp = w + (size_t)base * 128;
    float* ep = e_out + (size_t)base * 128;
    float r = 0.0f;
    #pragma unroll
    for (int i = 0; i < 128; i += 8) {       // numpy order within lane
        float e = (float)exp((double)(wp[i + k] - m));
        ep[i + k] = e;
        r += e;
    }
    smr[tid] = r; __syncthreads();
    if (k == 0)                               // numpy pairwise combine of 8 lanes
        bs[base] = ((smr[tid]+smr[tid+1])+(smr[tid+2]+smr[tid+3]))
                 + ((smr[tid+4]+smr[tid+5])+(smr[tid+6]+smr[tid+7]));
}

// p_i = e_i / Z (IEEE f32 div, matches np); histogram; numpy base-128 sum of p.
// Z recomputed REDUNDANTLY per block (numpy perfect tree over bs[1024]) -
// launch boundary is the sync; R8 lesson: grid spin-barriers cost ~70 us.
// p is NOT stored: downstream consumers recompute it bit-identically.
__global__ void k_prob_hist_sum(const float* __restrict__ probs, const float* __restrict__ bs,
                                unsigned int* __restrict__ hist, float* __restrict__ bs2) {
    __shared__ float sf[256];
    __shared__ float smr[256];
    int tid = threadIdx.x;
    const float* b4 = bs + tid * 4;
    sf[tid] = (b4[0] + b4[1]) + (b4[2] + b4[3]);   // bottom 2 tree levels
    __syncthreads();
    for (int n = 128; n >= 1; n >>= 1) {
        float t = 0.0f;
        if (tid < n) t = sf[2*tid] + sf[2*tid+1];
        __syncthreads();
        if (tid < n) sf[tid] = t;
        __syncthreads();
    }
    const float Z = sf[0];
    __syncthreads();

    int task = blockIdx.x * 256 + tid;
    int base = task >> 3;
    int k    = task & 7;
    const float* pp = probs + (size_t)base * 128;
    float r = 0.0f;
    #pragma unroll
    for (int i = 0; i < 128; i += 8) {
        float pv = pp[i + k] / Z;
        r += pv;
        atomicAdd(&hist[desc_key(pv) >> BSH], 1u);
    }
    smr[tid] = r; __syncthreads();
    if (k == 0)
        bs2[base] = ((smr[tid]+smr[tid+1])+(smr[tid+2]+smr[tid+3]))
                  + ((smr[tid+4]+smr[tid+5])+(smr[tid+6]+smr[tid+7]));
}

// ---------- bucket ranking sort ----------
// 256 blocks x 256 threads; each thread owns 4 consecutive buckets (uint4).
__global__ void k_scan_local(const unsigned int* __restrict__ hist,
                             unsigned int* __restrict__ local,
                             unsigned int* __restrict__ chunksum) {
    __shared__ unsigned int sm[256];
    int tid = threadIdx.x;
    int g0 = (blockIdx.x * 256 + tid) * 4;
    uint4 h = *(const uint4*)&hist[g0];
    unsigned int s = h.x + h.y + h.z + h.w;
    sm[tid] = s; __syncthreads();
    for (int off = 1; off < 256; off <<= 1) {
        unsigned int t = (tid >= off) ? sm[tid - off] : 0u;
        __syncthreads();
        sm[tid] += t;
        __syncthreads();
    }
    unsigned int excl = sm[tid] - s;
    uint4 o;
    o.x = excl; o.y = excl + h.x; o.z = o.y + h.y; o.w = o.z + h.z;
    *(uint4*)&local[g0] = o;
    if (tid == 255) chunksum[blockIdx.x] = sm[255];
}

// Scatter unique key (desc_prob_bits<<17)|idx into its bucket segment.
// chunkoff AND Z recomputed redundantly per block (bit-identical everywhere).
__global__ void k_scatter(const float* __restrict__ probs,   // holds e
                          const float* __restrict__ bs,
                          const unsigned int* __restrict__ local,
                          const unsigned int* __restrict__ chunksum,
                          unsigned int* __restrict__ cnt,
                          unsigned long long* __restrict__ bucketed) {
    __shared__ unsigned int su[256];
    __shared__ unsigned int sco[256];
    __shared__ float sf[256];
    int tid = threadIdx.x;
    unsigned int v = chunksum[tid];
    su[tid] = v; __syncthreads();
    for (int off = 1; off < 256; off <<= 1) {
        unsigned int t = (tid >= off) ? su[tid - off] : 0u;
        __syncthreads();
        su[tid] += t;
        __syncthreads();
    }
    sco[tid] = su[tid] - v;
    __syncthreads();
    // Z: numpy perfect tree over bs[1024]
    const float* b4 = bs + tid * 4;
    sf[tid] = (b4[0] + b4[1]) + (b4[2] + b4[3]);
    __syncthreads();
    for (int n = 128; n >= 1; n >>= 1) {
        float t = 0.0f;
        if (tid < n) t = sf[2*tid] + sf[2*tid+1];
        __syncthreads();
        if (tid < n) sf[tid] = t;
        __syncthreads();
    }
    const float Z = sf[0];
    __syncthreads();

    int i = blockIdx.x * 256 + tid;
    float pv = probs[i] / Z;                  // bit-identical to np's p_i
    unsigned int d = desc_key(pv);
    unsigned int b = d >> BSH;
    unsigned int base = sco[b >> 10] + local[b];
    unsigned int off = atomicAdd(&cnt[b], 1u);
    bucketed[base + off] = ((unsigned long long)d << 17) | (unsigned int)i;
}

// Exact global rank = bucket base + (# strictly smaller keys in bucket).
// Keys unique -> permutation -> deterministic. Equal probs order index-asc.
// pv is reconstructed EXACTLY from the key bits (desc_key is a bijection;
// softmax probs are >0 so sign bit is 0): pv = as_float(~d ^ 0x80000000).
__global__ void k_rank(const unsigned long long* __restrict__ bucketed,
                       const unsigned int* __restrict__ hist,
                       const unsigned int* __restrict__ local,
                       const unsigned int* __restrict__ chunksum,
                       const float* __restrict__ bs2,
                       uint2* __restrict__ ret_rs) {
    __shared__ unsigned int su[256];
    __shared__ unsigned int sco[256];
    __shared__ float sf[256];
    int tid = threadIdx.x;
    unsigned int v = chunksum[tid];
    su[tid] = v;
    const float* b4 = bs2 + tid * 4;
    sf[tid] = (b4[0] + b4[1]) + (b4[2] + b4[3]);
    __syncthreads();
    for (int off = 1; off < 256; off <<= 1) {
        unsigned int t = (tid >= off) ? su[tid - off] : 0u;
        __syncthreads();
        su[tid] += t;
        __syncthreads();
    }
    sco[tid] = su[tid] - v;
    __syncthreads();
    for (int n = 128; n >= 1; n >>= 1) {     // numpy tree -> S, then inv
        float t = 0.0f;
        if (tid < n) t = sf[2*tid] + sf[2*tid+1];
        __syncthreads();
        if (tid < n) sf[tid] = t;
        __syncthreads();
    }
    const float inv = 1.0f / (sf[0] + 1e-6f);

    int p = blockIdx.x * 256 + tid;
    unsigned long long kk = bucketed[p];
    unsigned int b = (unsigned int)(kk >> 31);        // (d<<17)>>31 == d>>14
    unsigned int start = sco[b >> 10] + local[b];
    unsigned int len = hist[b];
    unsigned int c = 0;
    for (unsigned int q = start; q < start + len; ++q)
        c += (bucketed[q] < kk) ? 1u : 0u;
    unsigned int rank = start + c;
    if (rank < NRET) {
        unsigned int idx = (unsigned int)(kk & 0x1FFFFu);
        unsigned int d = (unsigned int)(kk >> 17);
        float pv = __uint_as_float(~d ^ 0x80000000u);  // == probs[idx], exact
        ret_rs[rank] = make_uint2(idx, __float_as_uint(pv * inv));
    }
}

// ---------- final gather: R6 mapping + real 8-deep MLP (R8-proven ~22 us) ----
// block j -> xcd v=j&7, s=j>>3, batch b=v+8*(s>>5), slot=s&31; thread covers
// ranks slot*2048 + tid + 256k. launch_bounds(256,2) gives VGPR headroom so
// all 8 random loads are genuinely in flight (VGPR=32 serialized them in R6).
// R4: randomness stays on the READ side; R7: no unsynced cross-plane loops;
// R8: no grid spin-barriers.
__global__ __launch_bounds__(256, 2)
void k_gather(const float4* __restrict__ pts,
              const uint2* __restrict__ ret_rs,
              float4* __restrict__ out) {
    int j = blockIdx.x;
    int v = j & 7;
    int s = j >> 3;
    int b = v + ((s >> 5) << 3);
    int r0 = ((s & 31) << 11) + threadIdx.x;
    const float4* src = pts + (size_t)b * NPTS;
    float4* dst = out + (size_t)b * NRET;

    uint2 rs0 = ret_rs[r0];
    uint2 rs1 = ret_rs[r0 + 256];
    uint2 rs2 = ret_rs[r0 + 512];
    uint2 rs3 = ret_rs[r0 + 768];
    uint2 rs4 = ret_rs[r0 + 1024];
    uint2 rs5 = ret_rs[r0 + 1280];
    uint2 rs6 = ret_rs[r0 + 1536];
    uint2 rs7 = ret_rs[r0 + 1792];
    float4 v0 = src[rs0.x]; float4 v1 = src[rs1.x];
    float4 v2 = src[rs2.x]; float4 v3 = src[rs3.x];
    float4 v4 = src[rs4.x]; float4 v5 = src[rs5.x];
    float4 v6 = src[rs6.x]; float4 v7 = src[rs7.x];
    float c0 = __uint_as_float(rs0.y); float c1 = __uint_as_float(rs1.y);
    float c2 = __uint_as_float(rs2.y); float c3 = __uint_as_float(rs3.y);
    float c4 = __uint_as_float(rs4.y); float c5 = __uint_as_float(rs5.y);
    float c6 = __uint_as_float(rs6.y); float c7 = __uint_as_float(rs7.y);
    v0.x *= c0; v0.y *= c0; v0.z *= c0; v0.w *= c0; dst[r0]        = v0;
    v1.x *= c1; v1.y *= c1; v1.z *= c1; v1.w *= c1; dst[r0 + 256]  = v1;
    v2.x *= c2; v2.y *= c2; v2.z *= c2; v2.w *= c2; dst[r0 + 512]  = v2;
    v3.x *= c3; v3.y *= c3; v3.z *= c3; v3.w *= c3; dst[r0 + 768]  = v3;
    v4.x *= c4; v4.y *= c4; v4.z *= c4; v4.w *= c4; dst[r0 + 1024] = v4;
    v5.x *= c5; v5.y *= c5; v5.z *= c5; v5.w *= c5; dst[r0 + 1280] = v5;
    v6.x *= c6; v6.y *= c6; v6.z *= c6; v6.w *= c6; dst[r0 + 1536] = v6;
    v7.x *= c7; v7.y *= c7; v7.z *= c7; v7.w *= c7; dst[r0 + 1792] = v7;
}

extern "C" void kernel_launch(void* const* d_in, const int* in_sizes, int n_in,
                              void* d_out, int out_size, void* d_ws, size_t ws_size,
                              hipStream_t stream) {
    const float* pts = (const float*)d_in[0];   // [64, 131072, 4]
    const float* w   = (const float*)d_in[1];   // [131072]
    float* out = (float*)d_out;

    char* ws = (char*)d_ws;
    unsigned int* hist      = (unsigned int*)(ws + 0);                 // 1 MB
    unsigned int* cnt       = (unsigned int*)(ws + (1 << 20));         // 1 MB
    unsigned int* local     = (unsigned int*)(ws + (2 << 20));         // 1 MB
    unsigned int* chunksum  = (unsigned int*)(ws + (3 << 20));         // 1 KB
    float*        bs        = (float*)(ws + (3 << 20) + 16384);        // 4 KB
    float*        bs2       = (float*)(ws + (3 << 20) + 24576);        // 4 KB
    float*        probs     = (float*)(ws + (3 << 20) + (1 << 19));    // 512 KB (holds e)
    unsigned long long* bucketed = (unsigned long long*)(ws + (4 << 20)); // 1 MB
    uint2*        ret_rs    = (uint2*)(ws + (5 << 20));                // 512 KB

    k_zero_exp      <<<544, 256, 0, stream>>>(w, (uint4*)ws, probs, bs);
    k_prob_hist_sum <<<32,  256, 0, stream>>>(probs, bs, hist, bs2);
    k_scan_local    <<<256, 256, 0, stream>>>(hist, local, chunksum);
    k_scatter       <<<512, 256, 0, stream>>>(probs, bs, local, chunksum, cnt, bucketed);
    k_rank          <<<512, 256, 0, stream>>>(bucketed, hist, local, chunksum, bs2, ret_rs);
    k_gather        <<<2048, 256, 0, stream>>>((const float4*)pts, ret_rs, (float4*)out);
}

// Round 11
// 117.811 us; speedup vs baseline: 1.1283x; 1.1283x over previous
//
#include <hip/hip_runtime.h>
#include <hip/hip_bf16.h>
#include <cstdint>

// Problem constants
#define NPTS  131072
#define NRET  65536
#define NBAT  64
#define NBUCK (1 << 18)   // buckets = top-18 bits of descending key
#define BSH   14          // d >> 14 -> bucket

// Monotone map f32 -> u32 such that ascending u32 == DESCENDING float value.
__device__ __forceinline__ unsigned int desc_key(float w) {
    unsigned int b = __float_as_uint(w);
    unsigned int s = b ^ ((unsigned int)((int)b >> 31) | 0x80000000u); // ascending
    return ~s;                                                        // descending
}

// Fused: zero 2 MiB (hist+cnt) with all 512 blocks; blocks 0..255 also do the
// per-block partial max of w (exact, order-independent).
// R10 lesson: do NOT instead re-scan w redundantly in 32 blocks (+15 us serial).
__global__ void k_zero_pmax(const float* __restrict__ w, uint4* __restrict__ zp,
                            float* __restrict__ pmax) {
    int j = blockIdx.x, tid = threadIdx.x;
    zp[j * 256 + tid] = make_uint4(0u, 0u, 0u, 0u);
    if (j < 256) {
        __shared__ float sm[256];
        int i = j * 256 + tid;
        float m = fmaxf(w[i], w[i + 65536]);       // NPTS = 2*65536
        sm[tid] = m; __syncthreads();
        for (int off = 128; off > 0; off >>= 1) {
            if (tid < off) sm[tid] = fmaxf(sm[tid], sm[tid + off]);
            __syncthreads();
        }
        if (tid == 0) pmax[j] = sm[0];
    }
}

// e_i = correctly-rounded f32 exp(f32(w_i - m)) via double. One thread per
// numpy 8-accumulator LANE of each 128-elem base block; 8 lanes combined
// pairwise in numpy's order via LDS. Final max over pmax[256] done in-block.
// 32 blocks x 256 threads = 8192 tasks = 1024 base blocks x 8 lanes.
__global__ void k_exp_sum(const float* __restrict__ w, const float* __restrict__ pmax,
                          float* __restrict__ e_out, float* __restrict__ bs) {
    __shared__ float smm[256];
    __shared__ float smr[256];
    int tid = threadIdx.x;
    smm[tid] = pmax[tid]; __syncthreads();
    for (int off = 128; off > 0; off >>= 1) {
        if (tid < off) smm[tid] = fmaxf(smm[tid], smm[tid + off]);
        __syncthreads();
    }
    float m = smm[0];
    int task = blockIdx.x * 256 + tid;       // 0..8191
    int base = task >> 3;                    // base block 0..1023
    int k    = task & 7;                     // accumulator lane
    const float* wp = w + (size_t)base * 128;
    float* ep = e_out + (size_t)base * 128;
    float r = 0.0f;
    #pragma unroll
    for (int i = 0; i < 128; i += 8) {       // numpy order within lane
        float e = (float)exp((double)(wp[i + k] - m));
        ep[i + k] = e;
        r += e;
    }
    smr[tid] = r; __syncthreads();
    if (k == 0)                               // numpy pairwise combine of 8 lanes
        bs[base] = ((smr[tid]+smr[tid+1])+(smr[tid+2]+smr[tid+3]))
                 + ((smr[tid+4]+smr[tid+5])+(smr[tid+6]+smr[tid+7]));
}

// p_i = e_i / Z; histogram; numpy base-128 sum of p. Z is recomputed
// REDUNDANTLY per block (numpy perfect tree over bs[1024], bit-identical in
// every block - launch boundary provides the sync; R8 lesson: grid
// spin-barriers cost ~70 us each on this chip).
__global__ void k_prob_hist_sum(float* __restrict__ probs, const float* __restrict__ bs,
                                unsigned int* __restrict__ hist, float* __restrict__ bs2) {
    __shared__ float sf[256];
    __shared__ float smr[256];
    int tid = threadIdx.x;
    // Z: bottom 2 tree levels then 256-leaf perfect tree (numpy recursion shape)
    const float* b4 = bs + tid * 4;
    sf[tid] = (b4[0] + b4[1]) + (b4[2] + b4[3]);
    __syncthreads();
    for (int n = 128; n >= 1; n >>= 1) {
        float t = 0.0f;
        if (tid < n) t = sf[2*tid] + sf[2*tid+1];
        __syncthreads();
        if (tid < n) sf[tid] = t;
        __syncthreads();
    }
    const float Z = sf[0];
    __syncthreads();

    int task = blockIdx.x * 256 + tid;
    int base = task >> 3;
    int k    = task & 7;
    float* pp = probs + (size_t)base * 128;
    float r = 0.0f;
    #pragma unroll
    for (int i = 0; i < 128; i += 8) {
        float pv = pp[i + k] / Z;
        pp[i + k] = pv;
        r += pv;
        atomicAdd(&hist[desc_key(pv) >> BSH], 1u);
    }
    smr[tid] = r; __syncthreads();
    if (k == 0)
        bs2[base] = ((smr[tid]+smr[tid+1])+(smr[tid+2]+smr[tid+3]))
                  + ((smr[tid+4]+smr[tid+5])+(smr[tid+6]+smr[tid+7]));
}

// ---------- bucket ranking sort ----------
// 256 blocks x 256 threads; each thread owns 4 consecutive buckets (uint4).
__global__ void k_scan_local(const unsigned int* __restrict__ hist,
                             unsigned int* __restrict__ local,
                             unsigned int* __restrict__ chunksum) {
    __shared__ unsigned int sm[256];
    int tid = threadIdx.x;
    int g0 = (blockIdx.x * 256 + tid) * 4;
    uint4 h = *(const uint4*)&hist[g0];
    unsigned int s = h.x + h.y + h.z + h.w;
    sm[tid] = s; __syncthreads();
    for (int off = 1; off < 256; off <<= 1) {
        unsigned int t = (tid >= off) ? sm[tid - off] : 0u;
        __syncthreads();
        sm[tid] += t;
        __syncthreads();
    }
    unsigned int excl = sm[tid] - s;
    uint4 o;
    o.x = excl; o.y = excl + h.x; o.z = o.y + h.y; o.w = o.z + h.z;
    *(uint4*)&local[g0] = o;
    if (tid == 255) chunksum[blockIdx.x] = sm[255];
}

// Scatter unique key (desc_prob_bits<<17)|idx into its bucket segment.
// chunkoff recomputed redundantly per block (exact integer scan of 256).
__global__ void k_scatter(const float* __restrict__ probs,
                          const unsigned int* __restrict__ local,
                          const unsigned int* __restrict__ chunksum,
                          unsigned int* __restrict__ cnt,
                          unsigned long long* __restrict__ bucketed) {
    __shared__ unsigned int su[256];
    __shared__ unsigned int sco[256];
    int tid = threadIdx.x;
    unsigned int v = chunksum[tid];
    su[tid] = v; __syncthreads();
    for (int off = 1; off < 256; off <<= 1) {
        unsigned int t = (tid >= off) ? su[tid - off] : 0u;
        __syncthreads();
        su[tid] += t;
        __syncthreads();
    }
    sco[tid] = su[tid] - v;
    __syncthreads();
    int i = blockIdx.x * 256 + tid;
    unsigned int d = desc_key(probs[i]);
    unsigned int b = d >> BSH;
    unsigned int base = sco[b >> 10] + local[b];
    unsigned int off = atomicAdd(&cnt[b], 1u);
    bucketed[base + off] = ((unsigned long long)d << 17) | (unsigned int)i;
}

// Exact global rank = bucket base + (# strictly smaller keys in bucket).
// Keys unique -> permutation -> deterministic. Equal probs order index-asc.
// chunkoff + inv recomputed redundantly per block (bit-identical everywhere).
// pv reconstructed EXACTLY from key bits (desc_key bijective; probs > 0):
// pv = as_float(~d ^ 0x80000000) - saves a random probs[idx] read (R10-proven).
__global__ void k_rank(const unsigned long long* __restrict__ bucketed,
                       const unsigned int* __restrict__ hist,
                       const unsigned int* __restrict__ local,
                       const unsigned int* __restrict__ chunksum,
                       const float* __restrict__ bs2,
                       uint2* __restrict__ ret_rs) {
    __shared__ unsigned int su[256];
    __shared__ unsigned int sco[256];
    __shared__ float sf[256];
    int tid = threadIdx.x;
    unsigned int v = chunksum[tid];
    su[tid] = v;
    const float* b4 = bs2 + tid * 4;
    sf[tid] = (b4[0] + b4[1]) + (b4[2] + b4[3]);
    __syncthreads();
    for (int off = 1; off < 256; off <<= 1) {
        unsigned int t = (tid >= off) ? su[tid - off] : 0u;
        __syncthreads();
        su[tid] += t;
        __syncthreads();
    }
    sco[tid] = su[tid] - v;
    __syncthreads();
    for (int n = 128; n >= 1; n >>= 1) {     // numpy tree -> S, then inv
        float t = 0.0f;
        if (tid < n) t = sf[2*tid] + sf[2*tid+1];
        __syncthreads();
        if (tid < n) sf[tid] = t;
        __syncthreads();
    }
    const float inv = 1.0f / (sf[0] + 1e-6f);

    int p = blockIdx.x * 256 + tid;
    unsigned long long kk = bucketed[p];
    unsigned int b = (unsigned int)(kk >> 31);        // (d<<17)>>31 == d>>14
    unsigned int start = sco[b >> 10] + local[b];
    unsigned int len = hist[b];
    unsigned int c = 0;
    for (unsigned int q = start; q < start + len; ++q)
        c += (bucketed[q] < kk) ? 1u : 0u;
    unsigned int rank = start + c;
    if (rank < NRET) {
        unsigned int idx = (unsigned int)(kk & 0x1FFFFu);
        unsigned int d = (unsigned int)(kk >> 17);
        float pv = __uint_as_float(~d ^ 0x80000000u);  // == probs[idx], exact
        ret_rs[rank] = make_uint2(idx, __float_as_uint(pv * inv));
    }
}

// ---------- final gather: R6 mapping + real 8-deep MLP (R8/R9-proven ~22 us) --
// block j -> xcd v=j&7, s=j>>3, batch b=v+8*(s>>5), slot=s&31; thread covers
// ranks slot*2048 + tid + 256k. launch_bounds(256,2) gives VGPR headroom so
// all 8 random loads are genuinely in flight (VGPR=32 serialized them in R6).
// R4: randomness stays on the READ side; R7: no unsynced cross-plane loops;
// R8: no grid spin-barriers.
__global__ __launch_bounds__(256, 2)
void k_gather(const float4* __restrict__ pts,
              const uint2* __restrict__ ret_rs,
              float4* __restrict__ out) {
    int j = blockIdx.x;
    int v = j & 7;
    int s = j >> 3;
    int b = v + ((s >> 5) << 3);
    int r0 = ((s & 31) << 11) + threadIdx.x;
    const float4* src = pts + (size_t)b * NPTS;
    float4* dst = out + (size_t)b * NRET;

    uint2 rs0 = ret_rs[r0];
    uint2 rs1 = ret_rs[r0 + 256];
    uint2 rs2 = ret_rs[r0 + 512];
    uint2 rs3 = ret_rs[r0 + 768];
    uint2 rs4 = ret_rs[r0 + 1024];
    uint2 rs5 = ret_rs[r0 + 1280];
    uint2 rs6 = ret_rs[r0 + 1536];
    uint2 rs7 = ret_rs[r0 + 1792];
    float4 v0 = src[rs0.x]; float4 v1 = src[rs1.x];
    float4 v2 = src[rs2.x]; float4 v3 = src[rs3.x];
    float4 v4 = src[rs4.x]; float4 v5 = src[rs5.x];
    float4 v6 = src[rs6.x]; float4 v7 = src[rs7.x];
    float c0 = __uint_as_float(rs0.y); float c1 = __uint_as_float(rs1.y);
    float c2 = __uint_as_float(rs2.y); float c3 = __uint_as_float(rs3.y);
    float c4 = __uint_as_float(rs4.y); float c5 = __uint_as_float(rs5.y);
    float c6 = __uint_as_float(rs6.y); float c7 = __uint_as_float(rs7.y);
    v0.x *= c0; v0.y *= c0; v0.z *= c0; v0.w *= c0; dst[r0]        = v0;
    v1.x *= c1; v1.y *= c1; v1.z *= c1; v1.w *= c1; dst[r0 + 256]  = v1;
    v2.x *= c2; v2.y *= c2; v2.z *= c2; v2.w *= c2; dst[r0 + 512]  = v2;
    v3.x *= c3; v3.y *= c3; v3.z *= c3; v3.w *= c3; dst[r0 + 768]  = v3;
    v4.x *= c4; v4.y *= c4; v4.z *= c4; v4.w *= c4; dst[r0 + 1024] = v4;
    v5.x *= c5; v5.y *= c5; v5.z *= c5; v5.w *= c5; dst[r0 + 1280] = v5;
    v6.x *= c6; v6.y *= c6; v6.z *= c6; v6.w *= c6; dst[r0 + 1536] = v6;
    v7.x *= c7; v7.y *= c7; v7.z *= c7; v7.w *= c7; dst[r0 + 1792] = v7;
}

extern "C" void kernel_launch(void* const* d_in, const int* in_sizes, int n_in,
                              void* d_out, int out_size, void* d_ws, size_t ws_size,
                              hipStream_t stream) {
    const float* pts = (const float*)d_in[0];   // [64, 131072, 4]
    const float* w   = (const float*)d_in[1];   // [131072]
    float* out = (float*)d_out;

    char* ws = (char*)d_ws;
    unsigned int* hist      = (unsigned int*)(ws + 0);                 // 1 MB
    unsigned int* cnt       = (unsigned int*)(ws + (1 << 20));         // 1 MB
    unsigned int* local     = (unsigned int*)(ws + (2 << 20));         // 1 MB
    unsigned int* chunksum  = (unsigned int*)(ws + (3 << 20));         // 1 KB
    float*        pmax      = (float*)(ws + (3 << 20) + 8192);         // 1 KB
    float*        bs        = (float*)(ws + (3 << 20) + 16384);        // 4 KB
    float*        bs2       = (float*)(ws + (3 << 20) + 24576);        // 4 KB
    float*        probs     = (float*)(ws + (3 << 20) + (1 << 19));    // 512 KB @3.5MB
    unsigned long long* bucketed = (unsigned long long*)(ws + (4 << 20)); // 1 MB
    uint2*        ret_rs    = (uint2*)(ws + (5 << 20));                // 512 KB

    k_zero_pmax     <<<512, 256, 0, stream>>>(w, (uint4*)ws, pmax);
    k_exp_sum       <<<32,  256, 0, stream>>>(w, pmax, probs, bs);    // probs = e
    k_prob_hist_sum <<<32,  256, 0, stream>>>(probs, bs, hist, bs2);  // probs = p
    k_scan_local    <<<256, 256, 0, stream>>>(hist, local, chunksum);
    k_scatter       <<<512, 256, 0, stream>>>(probs, local, chunksum, cnt, bucketed);
    k_rank          <<<512, 256, 0, stream>>>(bucketed, hist, local, chunksum,
                                              bs2, ret_rs);
    k_gather        <<<2048, 256, 0, stream>>>((const float4*)pts, ret_rs, (float4*)out);
}

// Round 12
// 117.341 us; speedup vs baseline: 1.1328x; 1.0040x over previous
//
#include <hip/hip_runtime.h>
#include <hip/hip_bf16.h>
#include <cstdint>

// Problem constants
#define NPTS  131072
#define NRET  65536
#define NBAT  64
#define NBUCK (1 << 18)   // buckets = top-18 bits of descending key
#define BSH   14          // d >> 14 -> bucket

// Monotone map f32 -> u32 such that ascending u32 == DESCENDING float value.
__device__ __forceinline__ unsigned int desc_key(float w) {
    unsigned int b = __float_as_uint(w);
    unsigned int s = b ^ ((unsigned int)((int)b >> 31) | 0x80000000u); // ascending
    return ~s;                                                        // descending
}

// Fused: zero 2 MiB (hist+cnt) with all 512 blocks; blocks 0..255 also do the
// per-block partial max of w (exact, order-independent).
// R10 lesson: do NOT instead re-scan w redundantly in 32 blocks (+15 us serial).
__global__ void k_zero_pmax(const float* __restrict__ w, uint4* __restrict__ zp,
                            float* __restrict__ pmax) {
    int j = blockIdx.x, tid = threadIdx.x;
    zp[j * 256 + tid] = make_uint4(0u, 0u, 0u, 0u);
    if (j < 256) {
        __shared__ float sm[256];
        int i = j * 256 + tid;
        float m = fmaxf(w[i], w[i + 65536]);       // NPTS = 2*65536
        sm[tid] = m; __syncthreads();
        for (int off = 128; off > 0; off >>= 1) {
            if (tid < off) sm[tid] = fmaxf(sm[tid], sm[tid + off]);
            __syncthreads();
        }
        if (tid == 0) pmax[j] = sm[0];
    }
}

// e_i = correctly-rounded f32 exp(f32(w_i - m)) via double. One thread per
// numpy 8-accumulator LANE of each 128-elem base block; 8 lanes combined
// pairwise in numpy's order via LDS. Final max over pmax[256] done in-block.
// 32 blocks x 256 threads = 8192 tasks = 1024 base blocks x 8 lanes.
__global__ void k_exp_sum(const float* __restrict__ w, const float* __restrict__ pmax,
                          float* __restrict__ e_out, float* __restrict__ bs) {
    __shared__ float smm[256];
    __shared__ float smr[256];
    int tid = threadIdx.x;
    smm[tid] = pmax[tid]; __syncthreads();
    for (int off = 128; off > 0; off >>= 1) {
        if (tid < off) smm[tid] = fmaxf(smm[tid], smm[tid + off]);
        __syncthreads();
    }
    float m = smm[0];
    int task = blockIdx.x * 256 + tid;       // 0..8191
    int base = task >> 3;                    // base block 0..1023
    int k    = task & 7;                     // accumulator lane
    const float* wp = w + (size_t)base * 128;
    float* ep = e_out + (size_t)base * 128;
    float r = 0.0f;
    #pragma unroll
    for (int i = 0; i < 128; i += 8) {       // numpy order within lane
        float e = (float)exp((double)(wp[i + k] - m));
        ep[i + k] = e;
        r += e;
    }
    smr[tid] = r; __syncthreads();
    if (k == 0)                               // numpy pairwise combine of 8 lanes
        bs[base] = ((smr[tid]+smr[tid+1])+(smr[tid+2]+smr[tid+3]))
                 + ((smr[tid+4]+smr[tid+5])+(smr[tid+6]+smr[tid+7]));
}

// p_i = e_i / Z; histogram; numpy base-128 sum of p. Z is recomputed
// REDUNDANTLY per block (numpy perfect tree over bs[1024], bit-identical in
// every block - launch boundary provides the sync; R8 lesson: grid
// spin-barriers cost ~70 us each on this chip).
__global__ void k_prob_hist_sum(float* __restrict__ probs, const float* __restrict__ bs,
                                unsigned int* __restrict__ hist, float* __restrict__ bs2) {
    __shared__ float sf[256];
    __shared__ float smr[256];
    int tid = threadIdx.x;
    // Z: bottom 2 tree levels then 256-leaf perfect tree (numpy recursion shape)
    const float* b4 = bs + tid * 4;
    sf[tid] = (b4[0] + b4[1]) + (b4[2] + b4[3]);
    __syncthreads();
    for (int n = 128; n >= 1; n >>= 1) {
        float t = 0.0f;
        if (tid < n) t = sf[2*tid] + sf[2*tid+1];
        __syncthreads();
        if (tid < n) sf[tid] = t;
        __syncthreads();
    }
    const float Z = sf[0];
    __syncthreads();

    int task = blockIdx.x * 256 + tid;
    int base = task >> 3;
    int k    = task & 7;
    float* pp = probs + (size_t)base * 128;
    float r = 0.0f;
    #pragma unroll
    for (int i = 0; i < 128; i += 8) {
        float pv = pp[i + k] / Z;
        pp[i + k] = pv;
        r += pv;
        atomicAdd(&hist[desc_key(pv) >> BSH], 1u);
    }
    smr[tid] = r; __syncthreads();
    if (k == 0)
        bs2[base] = ((smr[tid]+smr[tid+1])+(smr[tid+2]+smr[tid+3]))
                  + ((smr[tid+4]+smr[tid+5])+(smr[tid+6]+smr[tid+7]));
}

// ---------- bucket ranking sort ----------
// 256 blocks x 256 threads; each thread owns 4 consecutive buckets (uint4).
__global__ void k_scan_local(const unsigned int* __restrict__ hist,
                             unsigned int* __restrict__ local,
                             unsigned int* __restrict__ chunksum) {
    __shared__ unsigned int sm[256];
    int tid = threadIdx.x;
    int g0 = (blockIdx.x * 256 + tid) * 4;
    uint4 h = *(const uint4*)&hist[g0];
    unsigned int s = h.x + h.y + h.z + h.w;
    sm[tid] = s; __syncthreads();
    for (int off = 1; off < 256; off <<= 1) {
        unsigned int t = (tid >= off) ? sm[tid - off] : 0u;
        __syncthreads();
        sm[tid] += t;
        __syncthreads();
    }
    unsigned int excl = sm[tid] - s;
    uint4 o;
    o.x = excl; o.y = excl + h.x; o.z = o.y + h.y; o.w = o.z + h.z;
    *(uint4*)&local[g0] = o;
    if (tid == 255) chunksum[blockIdx.x] = sm[255];
}

// Scatter unique key (desc_prob_bits<<17)|idx into its bucket segment.
// chunkoff recomputed redundantly per block (exact integer scan of 256).
__global__ void k_scatter(const float* __restrict__ probs,
                          const unsigned int* __restrict__ local,
                          const unsigned int* __restrict__ chunksum,
                          unsigned int* __restrict__ cnt,
                          unsigned long long* __restrict__ bucketed) {
    __shared__ unsigned int su[256];
    __shared__ unsigned int sco[256];
    int tid = threadIdx.x;
    unsigned int v = chunksum[tid];
    su[tid] = v; __syncthreads();
    for (int off = 1; off < 256; off <<= 1) {
        unsigned int t = (tid >= off) ? su[tid - off] : 0u;
        __syncthreads();
        su[tid] += t;
        __syncthreads();
    }
    sco[tid] = su[tid] - v;
    __syncthreads();
    int i = blockIdx.x * 256 + tid;
    unsigned int d = desc_key(probs[i]);
    unsigned int b = d >> BSH;
    unsigned int base = sco[b >> 10] + local[b];
    unsigned int off = atomicAdd(&cnt[b], 1u);
    bucketed[base + off] = ((unsigned long long)d << 17) | (unsigned int)i;
}

// Exact global rank = bucket base + (# strictly smaller keys in bucket).
// Keys unique -> permutation -> deterministic. Equal probs order index-asc.
// chunkoff + inv recomputed redundantly per block (bit-identical everywhere).
// pv reconstructed EXACTLY from key bits (desc_key bijective; probs > 0).
__global__ void k_rank(const unsigned long long* __restrict__ bucketed,
                       const unsigned int* __restrict__ hist,
                       const unsigned int* __restrict__ local,
                       const unsigned int* __restrict__ chunksum,
                       const float* __restrict__ bs2,
                       uint2* __restrict__ ret_rs) {
    __shared__ unsigned int su[256];
    __shared__ unsigned int sco[256];
    __shared__ float sf[256];
    int tid = threadIdx.x;
    unsigned int v = chunksum[tid];
    su[tid] = v;
    const float* b4 = bs2 + tid * 4;
    sf[tid] = (b4[0] + b4[1]) + (b4[2] + b4[3]);
    __syncthreads();
    for (int off = 1; off < 256; off <<= 1) {
        unsigned int t = (tid >= off) ? su[tid - off] : 0u;
        __syncthreads();
        su[tid] += t;
        __syncthreads();
    }
    sco[tid] = su[tid] - v;
    __syncthreads();
    for (int n = 128; n >= 1; n >>= 1) {     // numpy tree -> S, then inv
        float t = 0.0f;
        if (tid < n) t = sf[2*tid] + sf[2*tid+1];
        __syncthreads();
        if (tid < n) sf[tid] = t;
        __syncthreads();
    }
    const float inv = 1.0f / (sf[0] + 1e-6f);

    int p = blockIdx.x * 256 + tid;
    unsigned long long kk = bucketed[p];
    unsigned int b = (unsigned int)(kk >> 31);        // (d<<17)>>31 == d>>14
    unsigned int start = sco[b >> 10] + local[b];
    unsigned int len = hist[b];
    unsigned int c = 0;
    for (unsigned int q = start; q < start + len; ++q)
        c += (bucketed[q] < kk) ? 1u : 0u;
    unsigned int rank = start + c;
    if (rank < NRET) {
        unsigned int idx = (unsigned int)(kk & 0x1FFFFu);
        unsigned int d = (unsigned int)(kk >> 17);
        float pv = __uint_as_float(~d ^ 0x80000000u);  // == probs[idx], exact
        ret_rs[rank] = make_uint2(idx, __float_as_uint(pv * inv));
    }
}

// ---------- final gather: R11 mapping + forced 2-blocks/CU L2 confinement ----
// block j -> xcd v=j&7, s=j>>3, batch b=v+8*(s>>5), slot=s&31; thread covers
// ranks slot*2048 + tid + 256k (8 independent random 16 B reads).
// NEW (R12): 64 KB dummy LDS caps residency at 2 blocks/CU -> 64 blocks/XCD
// = exactly 2 batch groups = 4 MiB read window ~= L2 capacity, so the avg
// 2.13-rows-per-line reuse becomes an L2 hit instead of an L3 refetch.
// (R11 measured ~4 blocks/CU -> 8 MiB window -> partial L2 thrash, gather
// pinned at ~77 us / ~2.1 TB/s line-fill ceiling.) Discriminating experiment:
// thrash theory -> ~60 us; MSHR/latency theory -> ~90+ us.
// R4: randomness on READ side; R7: no unsynced loops; R8: no spin-barriers.
__global__ __launch_bounds__(256, 2)
void k_gather(const float4* __restrict__ pts,
              const uint2* __restrict__ ret_rs,
              float4* __restrict__ out) {
    __shared__ uint4 pad[4096];              // 64 KB occupancy limiter
    int j = blockIdx.x;
    int v = j & 7;
    int s = j >> 3;
    int b = v + ((s >> 5) << 3);
    int r0 = ((s & 31) << 11) + threadIdx.x;
    const float4* src = pts + (size_t)b * NPTS;
    float4* dst = out + (size_t)b * NRET;

    uint2 rs0 = ret_rs[r0];
    uint2 rs1 = ret_rs[r0 + 256];
    uint2 rs2 = ret_rs[r0 + 512];
    uint2 rs3 = ret_rs[r0 + 768];
    uint2 rs4 = ret_rs[r0 + 1024];
    uint2 rs5 = ret_rs[r0 + 1280];
    uint2 rs6 = ret_rs[r0 + 1536];
    uint2 rs7 = ret_rs[r0 + 1792];
    if (rs0.x == 0xDEADBEEFu) pad[rs1.x & 4095] = make_uint4(1u,1u,1u,1u); // never: idx < 2^17
    float4 v0 = src[rs0.x]; float4 v1 = src[rs1.x];
    float4 v2 = src[rs2.x]; float4 v3 = src[rs3.x];
    float4 v4 = src[rs4.x]; float4 v5 = src[rs5.x];
    float4 v6 = src[rs6.x]; float4 v7 = src[rs7.x];
    float c0 = __uint_as_float(rs0.y); float c1 = __uint_as_float(rs1.y);
    float c2 = __uint_as_float(rs2.y); float c3 = __uint_as_float(rs3.y);
    float c4 = __uint_as_float(rs4.y); float c5 = __uint_as_float(rs5.y);
    float c6 = __uint_as_float(rs6.y); float c7 = __uint_as_float(rs7.y);
    v0.x *= c0; v0.y *= c0; v0.z *= c0; v0.w *= c0; dst[r0]        = v0;
    v1.x *= c1; v1.y *= c1; v1.z *= c1; v1.w *= c1; dst[r0 + 256]  = v1;
    v2.x *= c2; v2.y *= c2; v2.z *= c2; v2.w *= c2; dst[r0 + 512]  = v2;
    v3.x *= c3; v3.y *= c3; v3.z *= c3; v3.w *= c3; dst[r0 + 768]  = v3;
    v4.x *= c4; v4.y *= c4; v4.z *= c4; v4.w *= c4; dst[r0 + 1024] = v4;
    v5.x *= c5; v5.y *= c5; v5.z *= c5; v5.w *= c5; dst[r0 + 1280] = v5;
    v6.x *= c6; v6.y *= c6; v6.z *= c6; v6.w *= c6; dst[r0 + 1536] = v6;
    v7.x *= c7; v7.y *= c7; v7.z *= c7; v7.w *= c7; dst[r0 + 1792] = v7;
}

extern "C" void kernel_launch(void* const* d_in, const int* in_sizes, int n_in,
                              void* d_out, int out_size, void* d_ws, size_t ws_size,
                              hipStream_t stream) {
    const float* pts = (const float*)d_in[0];   // [64, 131072, 4]
    const float* w   = (const float*)d_in[1];   // [131072]
    float* out = (float*)d_out;

    char* ws = (char*)d_ws;
    unsigned int* hist      = (unsigned int*)(ws + 0);                 // 1 MB
    unsigned int* cnt       = (unsigned int*)(ws + (1 << 20));         // 1 MB
    unsigned int* local     = (unsigned int*)(ws + (2 << 20));         // 1 MB
    unsigned int* chunksum  = (unsigned int*)(ws + (3 << 20));         // 1 KB
    float*        pmax      = (float*)(ws + (3 << 20) + 8192);         // 1 KB
    float*        bs        = (float*)(ws + (3 << 20) + 16384);        // 4 KB
    float*        bs2       = (float*)(ws + (3 << 20) + 24576);        // 4 KB
    float*        probs     = (float*)(ws + (3 << 20) + (1 << 19));    // 512 KB @3.5MB
    unsigned long long* bucketed = (unsigned long long*)(ws + (4 << 20)); // 1 MB
    uint2*        ret_rs    = (uint2*)(ws + (5 << 20));                // 512 KB

    k_zero_pmax     <<<512, 256, 0, stream>>>(w, (uint4*)ws, pmax);
    k_exp_sum       <<<32,  256, 0, stream>>>(w, pmax, probs, bs);    // probs = e
    k_prob_hist_sum <<<32,  256, 0, stream>>>(probs, bs, hist, bs2);  // probs = p
    k_scan_local    <<<256, 256, 0, stream>>>(hist, local, chunksum);
    k_scatter       <<<512, 256, 0, stream>>>(probs, local, chunksum, cnt, bucketed);
    k_rank          <<<512, 256, 0, stream>>>(bucketed, hist, local, chunksum,
                                              bs2, ret_rs);
    k_gather        <<<2048, 256, 0, stream>>>((const float4*)pts, ret_rs, (float4*)out);
}